// Round 1
// baseline (21.638 us; speedup 1.0000x reference)
//
#include <hip/hip_runtime.h>

// HeightVoxelLoss: B=2, X=200, Y=200, Z=16, C=17, CHOOSE=4000, HEIGHT=16 (h=1)
// loss = mean_b [ sum_valid SmoothL1(w[b,z] * log(softmax(preds)[label] + 1e-3)) / n_valid[b] ]
// w[b,z] = counts>0 ? 3 * (1/3)^(counts/max_count) : 0

namespace {
constexpr int B_ = 2, DX = 200, DY = 200, DZ = 16, DC = 17;
constexpr int CHOOSE_ = 4000, HEIGHT_ = 16, HB = DZ / HEIGHT_;  // HB = 1
constexpr int EMPTY_ = 16;
constexpr int LOSS_BLK = 256;
constexpr int NBLK = (CHOOSE_ * DZ) / LOSS_BLK;  // 250 blocks per batch
constexpr float MAXW = 3.0f, RATIO = 1.0f / 3.0f;
}

__global__ void count_kernel(const int* __restrict__ labels,
                             const int* __restrict__ sel,
                             int* __restrict__ counts) {
  __shared__ int s_cnt[HEIGHT_];
  const int b = blockIdx.x;
  const int t = blockIdx.y * blockDim.x + threadIdx.x;
  if (threadIdx.x < HEIGHT_) s_cnt[threadIdx.x] = 0;
  __syncthreads();
  if (t < CHOOSE_) {
    const int x = sel[(b * CHOOSE_ + t) * 2 + 0];
    const int y = sel[(b * CHOOSE_ + t) * 2 + 1];
    const int* lp = labels + ((b * DX + x) * DY + y) * DZ;
#pragma unroll
    for (int z = 0; z < DZ; ++z) {
      if (lp[z] != EMPTY_) atomicAdd(&s_cnt[z / HB], 1);
    }
  }
  __syncthreads();
  if (threadIdx.x < HEIGHT_)
    atomicAdd(&counts[b * HEIGHT_ + threadIdx.x], s_cnt[threadIdx.x]);
}

__global__ void loss_kernel(const float* __restrict__ preds,
                            const int* __restrict__ labels,
                            const int* __restrict__ sel,
                            const int* __restrict__ counts,
                            float* __restrict__ partial) {
  __shared__ float s_w[HEIGHT_];
  __shared__ float s_red[LOSS_BLK];
  const int b = blockIdx.x;
  const int tid = threadIdx.x;

  // Recompute weights per block from counts (cheap: 16 ints).
  if (tid < HEIGHT_) {
    float mc = 1.0f;
#pragma unroll
    for (int i = 0; i < HEIGHT_; ++i)
      mc = fmaxf(mc, (float)counts[b * HEIGHT_ + i]);
    const float c = (float)counts[b * HEIGHT_ + tid];
    s_w[tid] = (c > 0.0f) ? MAXW * powf(RATIO, c / mc) : 0.0f;
  }
  __syncthreads();

  const int vid = blockIdx.y * LOSS_BLK + tid;  // exactly CHOOSE_*DZ per batch
  const int s = vid / DZ;
  const int z = vid % DZ;
  const int x = sel[(b * CHOOSE_ + s) * 2 + 0];
  const int y = sel[(b * CHOOSE_ + s) * 2 + 1];
  const int col = ((b * DX + x) * DY + y) * DZ + z;
  const int l = labels[col];

  float val = 0.0f;
  if (l != EMPTY_) {
    const float* p = preds + (size_t)col * DC;
    float mx = p[0];
#pragma unroll
    for (int i = 1; i < DC; ++i) mx = fmaxf(mx, p[i]);
    float se = 0.0f, pl = 0.0f;
#pragma unroll
    for (int i = 0; i < DC; ++i) {
      const float e = expf(p[i] - mx);
      se += e;
      if (i == l) pl = e;
    }
    const float wl = s_w[z / HB] * logf(pl / se + 0.001f);
    const float a = fabsf(wl);
    val = (a < 1.0f) ? 0.5f * wl * wl : a - 0.5f;
  }

  // Deterministic fixed-pattern tree reduction.
  s_red[tid] = val;
  __syncthreads();
  for (int off = LOSS_BLK / 2; off > 0; off >>= 1) {
    if (tid < off) s_red[tid] += s_red[tid + off];
    __syncthreads();
  }
  if (tid == 0) partial[b * NBLK + blockIdx.y] = s_red[0];
}

__global__ void final_kernel(const float* __restrict__ partial,
                             const int* __restrict__ counts,
                             float* __restrict__ out) {
  const int lane = threadIdx.x;  // 64 threads, one wave
  float total = 0.0f;
  for (int b = 0; b < B_; ++b) {
    float s = 0.0f;
    for (int i = lane; i < NBLK; i += 64) s += partial[b * NBLK + i];
#pragma unroll
    for (int off = 32; off > 0; off >>= 1) s += __shfl_down(s, off, 64);
    int nv = (lane < HEIGHT_) ? counts[b * HEIGHT_ + lane] : 0;
#pragma unroll
    for (int off = 32; off > 0; off >>= 1) nv += __shfl_down(nv, off, 64);
    if (lane == 0) total += s / fmaxf((float)nv, 1.0f);
  }
  if (lane == 0) out[0] = total * (1.0f / (float)B_);
}

extern "C" void kernel_launch(void* const* d_in, const int* in_sizes, int n_in,
                              void* d_out, int out_size, void* d_ws, size_t ws_size,
                              hipStream_t stream) {
  const float* preds = (const float*)d_in[0];
  const int* labels = (const int*)d_in[1];
  const int* sel = (const int*)d_in[2];

  int* counts = (int*)d_ws;                                        // B*16 ints
  float* partial = (float*)((char*)d_ws + B_ * HEIGHT_ * sizeof(int));  // B*NBLK floats
  float* out = (float*)d_out;

  hipMemsetAsync(counts, 0, B_ * HEIGHT_ * sizeof(int), stream);

  dim3 cgrid(B_, (CHOOSE_ + 255) / 256);
  count_kernel<<<cgrid, 256, 0, stream>>>(labels, sel, counts);

  dim3 lgrid(B_, NBLK);
  loss_kernel<<<lgrid, LOSS_BLK, 0, stream>>>(preds, labels, sel, counts, partial);

  final_kernel<<<1, 64, 0, stream>>>(partial, counts, out);
}